// Round 8
// baseline (70.147 us; speedup 1.0000x reference)
//
#include <hip/hip_runtime.h>
#include <stdint.h>
#include <math.h>

// CategoricalSampler: argmax_v( logits[b,s,v]*(log2e/T) + g2(v) ), g2 = -log2(-log2 u),
// u from JAX threefry2x32-20 partitionable path: bits[i] = x0^x1, key=(0,42), ctr=(0, i).
// Bit-scheme verified R2; value path verified R3/R5/R6/R7 (absmax=0).
//
// R4 lesson: direct __log2f(u) only — no cancellation forms (kills order at u->1 winners).
// R8: VGPR_Count=12 in R7 proved the compiler was NOT prefetching the 5 float4 loads
// (can't — no registers); each j-iter stalled on vmcnt mid-stream. Prologue-prefetch all
// 5 loads into registers (VGPR ~40 <= 64 keeps 8 waves/SIMD), then pure-VALU main loop.

constexpr int V = 128000;
constexpr int NROWS = 256;       // B*S
constexpr int TPB = 256;
constexpr int SPLITQ = 25;       // grid 6400 -> 8 blocks/CU resident
                                 // SEG=5120, J=5 exact

__device__ __forceinline__ uint32_t rotl_(uint32_t x, uint32_t r) {
#if __has_builtin(__builtin_rotateleft32)
  return __builtin_rotateleft32(x, r);   // fshl -> single v_alignbit_b32
#else
  return (x << r) | (x >> (32u - r));
#endif
}

// Threefry-2x32-20, key (0,42), counter (0, ctr). Caller pre-adds ks1=42 to ctr.
// ks0=0, ks1=42, ks2=0x1BD11BDA^42=0x1BD11BF0. Injections merged into add3 forms.
__device__ __forceinline__ uint32_t threefry_xor_pre(uint32_t x1 /* = ctr + 42 */) {
  uint32_t x0;
  x0 = x1;            x1 = rotl_(x1, 13) ^ x0;   // round 1: x0 = 0 + x1
  x0 += x1;           x1 = rotl_(x1, 15) ^ x0;
  x0 += x1;           x1 = rotl_(x1, 26) ^ x0;
  x0 += x1;           x1 = rotl_(x1,  6) ^ x0;
  x1 += 0x1BD11BF1u;  x0 = x0 + 42u + x1;        // inject1 (ks1 | ks2+1) + round-add fused
                      x1 = rotl_(x1, 17) ^ x0;
  x0 += x1;           x1 = rotl_(x1, 29) ^ x0;
  x0 += x1;           x1 = rotl_(x1, 16) ^ x0;
  x0 += x1;           x1 = rotl_(x1, 24) ^ x0;
  x1 += 2u;           x0 = x0 + 0x1BD11BF0u + x1; // inject2 (ks2 | ks0+2)
                      x1 = rotl_(x1, 13) ^ x0;
  x0 += x1;           x1 = rotl_(x1, 15) ^ x0;
  x0 += x1;           x1 = rotl_(x1, 26) ^ x0;
  x0 += x1;           x1 = rotl_(x1,  6) ^ x0;
  x1 += 45u;          x0 = x0 + x1;               // inject3 (ks0=0 | ks1+3)
                      x1 = rotl_(x1, 17) ^ x0;
  x0 += x1;           x1 = rotl_(x1, 29) ^ x0;
  x0 += x1;           x1 = rotl_(x1, 16) ^ x0;
  x0 += x1;           x1 = rotl_(x1, 24) ^ x0;
  x1 += 0x1BD11BF4u;  x0 = x0 + 42u + x1;        // inject4 (ks1 | ks2+4)
                      x1 = rotl_(x1, 13) ^ x0;
  x0 += x1;           x1 = rotl_(x1, 15) ^ x0;
  x0 += x1;           x1 = rotl_(x1, 26) ^ x0;
  x0 += x1;           x1 = rotl_(x1,  6) ^ x0;
  return (x0 + 0x1BD11BF0u) ^ (x1 + 5u);         // inject5 (ks2 | ks0+5) folded into output
}

__device__ __forceinline__ uint32_t mant_pack(uint32_t bits) {
#if __has_builtin(__builtin_amdgcn_alignbit)
  return __builtin_amdgcn_alignbit(127u, bits, 9u);  // (bits>>9)|0x3f800000
#else
  return (bits >> 9) | 0x3f800000u;
#endif
}

template <int SPLIT>
__global__ __launch_bounds__(TPB) void CategoricalSampler_stage1(
    const float* __restrict__ logits, const float* __restrict__ temp,
    float2* __restrict__ ws) {
  constexpr int SEG = V / SPLIT;
  constexpr int J = SEG / (TPB * 4);   // exact by construction
  const int b   = blockIdx.x;
  const int row = b / SPLIT;           // block-uniform -> scalar ops
  const int seg = b - row * SPLIT;
  const int t   = threadIdx.x;
  const float scale = 1.4426950408889634f / temp[0];
  const int segbase = seg * SEG;
  const float4* rp4 = reinterpret_cast<const float4*>(logits + (size_t)row * V + segbase);
  // counter base with ks1=42 pre-added: x1_init = cb42 + j*TPB*4 + k
  const uint32_t cb42 = (uint32_t)row * (uint32_t)V + (uint32_t)segbase
                      + (uint32_t)(t * 4) + 42u;

  // ---- prologue: prefetch ALL loads into registers (pure-VALU main loop) ----
  float4 L[J];
#pragma unroll
  for (int j = 0; j < J; ++j) L[j] = rp4[j * TPB + t];

  float best = -INFINITY;
  int bestCode = 0;                    // jk = j*4+k, inline consts

#pragma unroll
  for (int j = 0; j < J; ++j) {
    const uint32_t c0 = cb42 + (uint32_t)(j * TPB * 4);
#pragma unroll
    for (int k = 0; k < 4; ++k) {              // 4 independent threefry chains -> ILP
      const uint32_t bits = threefry_xor_pre(c0 + (uint32_t)k);
      const float u  = __uint_as_float(mant_pack(bits)) - 1.0f;  // [0,1); 0 -> -inf, loses
      const float s1 = __log2f(u);
      const float s2 = __log2f(-s1);           // g2 = -s2 (neg folds to VOP3 modifier)
      const float lk = (k == 0) ? L[j].x : (k == 1) ? L[j].y : (k == 2) ? L[j].z : L[j].w;
      const float val = fmaf(lk, scale, -s2);
      if (val > best) { best = val; bestCode = j * 4 + k; }  // ascending v: > keeps earliest
    }
  }

  // reconstruct global index: v = segbase + j*TPB*4 + t*4 + k
  int bestIdx = segbase + (bestCode >> 2) * (TPB * 4) + (t << 2) + (bestCode & 3);

  // wave-level argmax (64 lanes), lower index wins ties
#pragma unroll
  for (int off = 32; off > 0; off >>= 1) {
    const float ov = __shfl_down(best, off);
    const int   oi = __shfl_down(bestIdx, off);
    if (ov > best || (ov == best && oi < bestIdx)) { best = ov; bestIdx = oi; }
  }

  __shared__ float sv[TPB / 64];
  __shared__ int   si[TPB / 64];
  const int wid = t >> 6;
  if ((t & 63) == 0) { sv[wid] = best; si[wid] = bestIdx; }
  __syncthreads();
  if (t == 0) {
    float bv = sv[0]; int bi = si[0];
#pragma unroll
    for (int w = 1; w < TPB / 64; ++w) {
      if (sv[w] > bv || (sv[w] == bv && si[w] < bi)) { bv = sv[w]; bi = si[w]; }
    }
    ws[b] = make_float2(bv, __int_as_float(bi));
  }
}

template <int SPLIT>
__global__ __launch_bounds__(64) void CategoricalSampler_stage2(
    const float2* __restrict__ ws, int* __restrict__ out) {
  const int r = blockIdx.x;            // one wave per row
  const int l = threadIdx.x;
  float best = -INFINITY;
  int bestIdx = 0x7FFFFFFF;
  if (l < SPLIT) {
    const float2 p = ws[r * SPLIT + l];
    best = p.x; bestIdx = __float_as_int(p.y);
  }
#pragma unroll
  for (int off = 32; off > 0; off >>= 1) {
    const float ov = __shfl_down(best, off);
    const int   oi = __shfl_down(bestIdx, off);
    if (ov > best || (ov == best && oi < bestIdx)) { best = ov; bestIdx = oi; }
  }
  if (l == 0) out[r] = bestIdx;
}

extern "C" void kernel_launch(void* const* d_in, const int* in_sizes, int n_in,
                              void* d_out, int out_size, void* d_ws, size_t ws_size,
                              hipStream_t stream) {
  const float* logits = (const float*)d_in[0];
  const float* temp   = (const float*)d_in[1];
  int* out = (int*)d_out;
  float2* ws = (float2*)d_ws;
  if (ws_size >= (size_t)NROWS * SPLITQ * sizeof(float2)) {
    CategoricalSampler_stage1<SPLITQ><<<NROWS * SPLITQ, TPB, 0, stream>>>(logits, temp, ws);
    CategoricalSampler_stage2<SPLITQ><<<NROWS, 64, 0, stream>>>(ws, out);
  } else {
    CategoricalSampler_stage1<5><<<NROWS * 5, TPB, 0, stream>>>(logits, temp, ws);
    CategoricalSampler_stage2<5><<<NROWS, 64, 0, stream>>>(ws, out);
  }
}